// Round 14
// baseline (130.840 us; speedup 1.0000x reference)
//
#include <hip/hip_runtime.h>
#include <hip/hip_bf16.h>
#include <math.h>

#define Bb 4
#define Nn 2048
#define Cc 640
#define Hh 10
#define Dd 64
#define EPSf 1e-5f
// ATTN_SCALE * log2(e), folded into Q affine so softmax is raw exp2
#define QSCALE 0.18033688f
#define KVT 64

typedef __attribute__((ext_vector_type(8))) short bf16x8;
typedef __attribute__((ext_vector_type(4))) float f32x4;
typedef __attribute__((ext_vector_type(16))) float f32x16;
typedef __attribute__((ext_vector_type(8))) unsigned short u16x8;
typedef __attribute__((ext_vector_type(4))) unsigned int u32x4;
typedef __attribute__((ext_vector_type(2))) unsigned int u32x2v;

__device__ inline unsigned short f2bf(float f) {
    unsigned int x = __float_as_uint(f);
    unsigned int r = (x + 0x7fffu + ((x >> 16) & 1u)) >> 16;
    return (unsigned short)r;
}
__device__ inline float bf2f(unsigned short v) {
    return __uint_as_float(((unsigned int)v) << 16);
}
__device__ inline unsigned pkbf(float a, float b) {
    __hip_bfloat162 t = __float22bfloat162_rn(float2{a, b});
    union { __hip_bfloat162 h; unsigned u; } cv; cv.h = t;
    return cv.u;
}
// single-instruction packed f32->bf16 (hot path only; <=1ulp vs RN)
__device__ inline unsigned cvtpk(float lo, float hi) {
    unsigned r;
    asm("v_cvt_pk_bf16_f32 %0, %1, %2" : "=v"(r) : "v"(lo), "v"(hi));
    return r;
}
__device__ inline f32x4 mfma16(bf16x8 a, bf16x8 b, f32x4 c) {
    return __builtin_amdgcn_mfma_f32_16x16x32_bf16(a, b, c, 0, 0, 0);
}
__device__ inline f32x16 mfma32(bf16x8 a, bf16x8 b, f32x16 c) {
    return __builtin_amdgcn_mfma_f32_32x32x16_bf16(a, b, c, 0, 0, 0);
}
// async global->LDS, 16B per lane; lds base must be wave-uniform (HW adds lane*16)
__device__ inline void gl16(const ushort* g, char* l) {
    __builtin_amdgcn_global_load_lds(
        (const __attribute__((address_space(1))) unsigned int*)g,
        (__attribute__((address_space(3))) unsigned int*)l, 16, 0, 0);
}

// ---------------- fused fp32 -> bf16 conversion for hs + 4 weights ----------------
__global__ __launch_bounds__(256)
void tobf16_all(const float* __restrict__ hs, const float* __restrict__ wq,
                const float* __restrict__ wk, const float* __restrict__ wv,
                const float* __restrict__ wo,
                ushort* __restrict__ Xb, ushort* __restrict__ Wqb,
                ushort* __restrict__ Wkb, ushort* __restrict__ Wvb,
                ushort* __restrict__ Wob) {
    const int bid = blockIdx.x;
    const float* src;
    ushort* dst;
    int i;
    if (bid < 2560) {
        src = hs; dst = Xb; i = bid * 256 + threadIdx.x;
    } else {
        int w = (bid - 2560) / 200;
        int rb = (bid - 2560) % 200;
        src = (w == 0) ? wq : (w == 1) ? wk : (w == 2) ? wv : wo;
        dst = (w == 0) ? Wqb : (w == 1) ? Wkb : (w == 2) ? Wvb : Wob;
        i = rb * 256 + threadIdx.x;
    }
    const size_t base = (size_t)i * 8;
    float4 a = *reinterpret_cast<const float4*>(src + base);
    float4 b = *reinterpret_cast<const float4*>(src + base + 4);
    u16x8 o;
    o[0] = f2bf(a.x); o[1] = f2bf(a.y); o[2] = f2bf(a.z); o[3] = f2bf(a.w);
    o[4] = f2bf(b.x); o[5] = f2bf(b.y); o[6] = f2bf(b.z); o[7] = f2bf(b.w);
    *reinterpret_cast<u16x8*>(dst + base) = o;
}

// ---------------- bf16 MFMA GEMM-BT body: OUT[r,o] = sum_c X[r,c] * W[o,c] ----------------
// MODE 0 additionally accumulates per-(bh,slot,d) column sums/sumsq into Pstats
// (slot = row-tile index within batch; fixed-order reductions -> deterministic).
template<int MODE>
__device__ __forceinline__ void gemm_body(
    const ushort* __restrict__ X, const ushort* __restrict__ W,
    ushort* __restrict__ outh, float* __restrict__ outf,
    const float* __restrict__ bo, const float* __restrict__ hs,
    float* __restrict__ Pstats,
    int mt, int h, char* As, char* Bs)
{
    const int tid = threadIdx.x;
    const int wv = tid >> 6, lane = tid & 63;
    const int c = lane & 15, g = lane >> 4;
    const int r0 = mt * 128;
    const int xr0 = (MODE == 1 || MODE == 2) ? (r0 < Nn ? r0 : r0 + Nn) : r0;
    const int o0 = h * 64;

    const int grow = lane >> 3;
    const int gcol = ((((lane & 7) * 16) ^ ((lane >> 3) << 4)) >> 1);

    f32x4 acc[2][4];
    #pragma unroll
    for (int i = 0; i < 2; ++i)
        #pragma unroll
        for (int j = 0; j < 4; ++j)
            acc[i][j] = (f32x4){0.f, 0.f, 0.f, 0.f};

    for (int k0 = 0; k0 < Cc; k0 += 64) {
        __syncthreads();
        #pragma unroll
        for (int i = 0; i < 4; ++i) {
            int a = wv * 4 + i;
            gl16(X + (size_t)(xr0 + a * 8 + grow) * Cc + k0 + gcol, As + a * 1024);
        }
        #pragma unroll
        for (int i = 0; i < 2; ++i) {
            int bb = wv * 2 + i;
            gl16(W + (size_t)(o0 + bb * 8 + grow) * Cc + k0 + gcol, Bs + bb * 1024);
        }
        __syncthreads();

        bf16x8 xf[2][2], wf[4][2];
        #pragma unroll
        for (int rt = 0; rt < 2; ++rt) {
            int row = wv * 32 + rt * 16 + c;
            #pragma unroll
            for (int ks = 0; ks < 2; ++ks)
                xf[rt][ks] = *reinterpret_cast<const bf16x8*>(
                    As + row * 128 + ((ks * 64 + g * 16) ^ ((row & 7) << 4)));
        }
        #pragma unroll
        for (int ct = 0; ct < 4; ++ct) {
            int row = ct * 16 + c;
            #pragma unroll
            for (int ks = 0; ks < 2; ++ks)
                wf[ct][ks] = *reinterpret_cast<const bf16x8*>(
                    Bs + row * 128 + ((ks * 64 + g * 16) ^ ((row & 7) << 4)));
        }
        #pragma unroll
        for (int rt = 0; rt < 2; ++rt)
            #pragma unroll
            for (int ct = 0; ct < 4; ++ct)
                #pragma unroll
                for (int ks = 0; ks < 2; ++ks) {
                    if constexpr (MODE == 2)
                        acc[rt][ct] = mfma16(xf[rt][ks], wf[ct][ks], acc[rt][ct]);
                    else
                        acc[rt][ct] = mfma16(wf[ct][ks], xf[rt][ks], acc[rt][ct]);
                }
    }

    if constexpr (MODE == 0 || MODE == 1) {
        #pragma unroll
        for (int rt = 0; rt < 2; ++rt) {
            int r = r0 + wv * 32 + rt * 16 + c;
            int bi = r >> 11, n = r & 2047;
            #pragma unroll
            for (int ct = 0; ct < 4; ++ct) {
                int d0 = ct * 16 + g * 4;
                ushort4 v4;
                v4.x = f2bf(acc[rt][ct][0]); v4.y = f2bf(acc[rt][ct][1]);
                v4.z = f2bf(acc[rt][ct][2]); v4.w = f2bf(acc[rt][ct][3]);
                *reinterpret_cast<ushort4*>(&outh[(((size_t)(bi * Hh + h)) * Nn + n) * Dd + d0]) = v4;
            }
        }
    } else if constexpr (MODE == 2) {
        #pragma unroll
        for (int rt = 0; rt < 2; ++rt) {
            int r = r0 + wv * 32 + rt * 16 + g * 4;
            int kb = r >> 11, n = r & 2047;
            #pragma unroll
            for (int ct = 0; ct < 4; ++ct) {
                int d = ct * 16 + c;
                ushort4 v4;
                v4.x = f2bf(acc[rt][ct][0]); v4.y = f2bf(acc[rt][ct][1]);
                v4.z = f2bf(acc[rt][ct][2]); v4.w = f2bf(acc[rt][ct][3]);
                *reinterpret_cast<ushort4*>(&outh[(((size_t)(kb * Hh + h)) * Dd + d) * Nn + n]) = v4;
            }
        }
    } else {
        #pragma unroll
        for (int rt = 0; rt < 2; ++rt) {
            int r = r0 + wv * 32 + rt * 16 + c;
            #pragma unroll
            for (int ct = 0; ct < 4; ++ct) {
                int o = h * 64 + ct * 16 + g * 4;
                float4 bvv = *reinterpret_cast<const float4*>(&bo[o]);
                float4 hv = *reinterpret_cast<const float4*>(&hs[(size_t)r * Cc + o]);
                float4 ov;
                ov.x = acc[rt][ct][0] + bvv.x + hv.x;
                ov.y = acc[rt][ct][1] + bvv.y + hv.y;
                ov.z = acc[rt][ct][2] + bvv.z + hv.z;
                ov.w = acc[rt][ct][3] + bvv.w + hv.w;
                *reinterpret_cast<float4*>(&outf[(size_t)r * Cc + o]) = ov;
            }
        }
    }

    if constexpr (MODE == 0) {
        // ---- fused Q-stats: column sums/sumsq over this block's 128 rows
        __syncthreads();                       // all waves done reading As/Bs
        float* Sw  = (float*)As;               // [4][64]
        float* Sw2 = (float*)(As + 1024);      // [4][64]
        #pragma unroll
        for (int ct = 0; ct < 4; ++ct) {
            #pragma unroll
            for (int rg = 0; rg < 4; ++rg) {
                float a0 = acc[0][ct][rg], a1 = acc[1][ct][rg];
                float v = a0 + a1;
                float q = a0 * a0 + a1 * a1;
                #pragma unroll
                for (int m = 1; m < 16; m <<= 1) {
                    v += __shfl_xor(v, m);
                    q += __shfl_xor(q, m);
                }
                if (c == 0) {
                    int d = ct * 16 + g * 4 + rg;
                    Sw[wv * 64 + d] = v;
                    Sw2[wv * 64 + d] = q;
                }
            }
        }
        __syncthreads();
        if (tid < 64) {
            float s = Sw[tid] + Sw[64 + tid] + Sw[128 + tid] + Sw[192 + tid];
            float q = Sw2[tid] + Sw2[64 + tid] + Sw2[128 + tid] + Sw2[192 + tid];
            int bi = mt >> 4, slot = mt & 15;
            int bh = bi * Hh + h;
            float* p = Pstats + ((size_t)(bh * 16 + slot) * 2) * 64;
            p[tid] = s;
            p[64 + tid] = q;
        }
    }
}

// Q, K, V projections fused into one 1280-block launch
__global__ __launch_bounds__(256)
void gemm_qkv(const ushort* __restrict__ X, const ushort* __restrict__ Wq,
              const ushort* __restrict__ Wk, const ushort* __restrict__ Wv,
              ushort* __restrict__ Qh, ushort* __restrict__ K16,
              ushort* __restrict__ Vt16, float* __restrict__ Pstats) {
    __shared__ alignas(16) char As[16384];
    __shared__ alignas(16) char Bs[8192];
    const int bx = blockIdx.x;
    if (bx < 64)
        gemm_body<0>(X, Wq, Qh, nullptr, nullptr, nullptr, Pstats, bx, blockIdx.y, As, Bs);
    else if (bx < 96)
        gemm_body<1>(X, Wk, K16, nullptr, nullptr, nullptr, nullptr, bx - 64, blockIdx.y, As, Bs);
    else
        gemm_body<2>(X, Wv, Vt16, nullptr, nullptr, nullptr, nullptr, bx - 96, blockIdx.y, As, Bs);
}

__global__ __launch_bounds__(256)
void gemm_out(const ushort* __restrict__ Ain, const ushort* __restrict__ Wo,
              float* __restrict__ out, const float* __restrict__ bo,
              const float* __restrict__ hs) {
    __shared__ alignas(16) char As[16384];
    __shared__ alignas(16) char Bs[8192];
    gemm_body<3>(Ain, Wo, nullptr, out, bo, hs, nullptr, blockIdx.x, blockIdx.y, As, Bs);
}

// ---------------- bf16 MFMA flash attention, v11 ----------------
// R12-proven single-buffer structure + LDS-stats prologue + s_setprio around MFMA.
// grid (40 bh, 16 qtiles), 8 waves (512 thr), waves 0-3 kv [0,1024), waves 4-7
// kv [1024,2048), KV tile 64. Fused adain on Q load (stats reduced from Pstats).
// Shift-free softmax (bare v_exp_f32); P pack via v_cvt_pk_bf16_f32.
__global__ __launch_bounds__(512, 4)
void attn_mfma(const ushort* __restrict__ Qh, const float* __restrict__ Pstats,
               const ushort* __restrict__ Kb, const ushort* __restrict__ Vtb,
               ushort* __restrict__ Ao) {
    __shared__ alignas(16) char smem[32768];   // Ks[2][8192] | Vs[2][8192]
    __shared__ float lsh[8][32];
    __shared__ float statl[4][64];             // mS, sS, mT, sT

    const int tid = threadIdx.x;
    const int wid = tid >> 6, lane = tid & 63;
    const int half = wid >> 2, wq = wid & 3;
    const int q31 = lane & 31, hi = lane >> 5;
    const int bh = blockIdx.x, b = bh / Hh, h = bh % Hh, kb = b >> 1;
    const int qw0 = blockIdx.y * 128 + wq * 32;
    const int kv0 = half * (Nn / 2);

    char* Ksh = smem + half * 8192;
    char* Vsh = smem + 16384 + half * 8192;

    const ushort* qp = Qh + ((size_t)bh * Nn + qw0) * Dd;
    const ushort* kp = Kb + ((size_t)(kb * Hh + h) * Nn + kv0) * Dd;
    const ushort* vp = Vtb + ((size_t)(kb * Hh + h)) * Dd * Nn + kv0;

    // ---- reduce Q stats from per-tile partials (odd batches only)
    if (b & 1) {
        if (tid < 128) {
            const int which = tid >> 6;     // 0: self(bh), 1: style(bh-Hh)
            const int d = tid & 63;
            const int tb = which ? (bh - Hh) : bh;
            const float* p = Pstats + ((size_t)(tb * 16) * 2) * 64;
            float s = 0.f, q = 0.f;
            #pragma unroll
            for (int j = 0; j < 16; ++j) {
                s += p[(j * 2) * 64 + d];
                q += p[(j * 2 + 1) * 64 + d];
            }
            float mu = s / (float)Nn;
            float var = (q - (float)Nn * mu * mu) / (float)(Nn - 1);
            float sd = sqrtf(var + EPSf);
            statl[which * 2 + 0][d] = mu;
            statl[which * 2 + 1][d] = sd;
        }
        __syncthreads();
    }

    // ---- Q fragments with fused adain + QSCALE (once per wave)
    bf16x8 qf[4];
    #pragma unroll
    for (int dsl = 0; dsl < 4; ++dsl) {
        const int d0 = dsl * 16 + hi * 8;
        u16x8 qin = *reinterpret_cast<const u16x8*>(qp + (size_t)q31 * Dd + d0);
        float x[8];
        #pragma unroll
        for (int j = 0; j < 8; ++j) x[j] = bf2f(qin[j]);
        if (b & 1) {
            #pragma unroll
            for (int j = 0; j < 8; ++j) {
                float r = statl[3][d0 + j] / statl[1][d0 + j];
                x[j] = (x[j] * r + (statl[2][d0 + j] - statl[0][d0 + j] * r)) * QSCALE;
            }
        } else {
            #pragma unroll
            for (int j = 0; j < 8; ++j) x[j] *= QSCALE;
        }
        u32x4 pw = {pkbf(x[0], x[1]), pkbf(x[2], x[3]), pkbf(x[4], x[5]), pkbf(x[6], x[7])};
        qf[dsl] = *reinterpret_cast<bf16x8*>(&pw);
    }

    f32x16 acc0, acc1;
    #pragma unroll
    for (int r = 0; r < 16; ++r) { acc0[r] = 0.f; acc1[r] = 0.f; }
    float l = 0.f;

    const int htid = tid & 255;
    const int srow = htid >> 3, sch = htid & 7;
    const int swz = (sch * 16) ^ ((srow & 7) << 4);
    const int soff0 = srow * 128 + swz;
    const int soff1 = (srow + 32) * 128 + swz;
    const ushort* kg0 = kp + (size_t)srow * Dd + sch * 8;
    const ushort* kg1 = kp + (size_t)(srow + 32) * Dd + sch * 8;
    const ushort* vg0 = vp + (size_t)srow * Nn + sch * 8;
    const ushort* vg1 = vp + (size_t)(srow + 32) * Nn + sch * 8;

    bf16x8 kr0 = *reinterpret_cast<const bf16x8*>(kg0);
    bf16x8 kr1 = *reinterpret_cast<const bf16x8*>(kg1);
    bf16x8 vr0 = *reinterpret_cast<const bf16x8*>(vg0);
    bf16x8 vr1 = *reinterpret_cast<const bf16x8*>(vg1);
    *reinterpret_cast<bf16x8*>(Ksh + soff0) = kr0;
    *reinterpret_cast<bf16x8*>(Ksh + soff1) = kr1;
    *reinterpret_cast<bf16x8*>(Vsh + soff0) = vr0;
    *reinterpret_cast<bf16x8*>(Vsh + soff1) = vr1;
    __syncthreads();

    const int kx = (q31 & 7) << 4;

    for (int kt = 0; kt < Nn / 2; kt += KVT) {
        const bool has_next = (kt + KVT) < (Nn / 2);
        if (has_next) {
            kr0 = *reinterpret_cast<const bf16x8*>(kg0 + (size_t)(kt + KVT) * Dd);
            kr1 = *reinterpret_cast<const bf16x8*>(kg1 + (size_t)(kt + KVT) * Dd);
            vr0 = *reinterpret_cast<const bf16x8*>(vg0 + kt + KVT);
            vr1 = *reinterpret_cast<const bf16x8*>(vg1 + kt + KVT);
        }

        // ---- QK^T (swapped): A=K rows, B=Q rows
        f32x16 st0, st1;
        #pragma unroll
        for (int r = 0; r < 16; ++r) { st0[r] = 0.f; st1[r] = 0.f; }
        __builtin_amdgcn_s_setprio(1);
        #pragma unroll
        for (int dsl = 0; dsl < 4; ++dsl) {
            bf16x8 kf0 = *reinterpret_cast<const bf16x8*>(
                Ksh + q31 * 128 + ((dsl * 32 + hi * 16) ^ kx));
            bf16x8 kf1 = *reinterpret_cast<const bf16x8*>(
                Ksh + (q31 + 32) * 128 + ((dsl * 32 + hi * 16) ^ kx));
            st0 = mfma32(kf0, qf[dsl], st0);
            st1 = mfma32(kf1, qf[dsl], st1);
        }
        __builtin_amdgcn_s_setprio(0);

        // ---- P = exp2(s) raw, bare v_exp_f32 (shift-free softmax)
        #pragma unroll
        for (int r = 0; r < 16; ++r) st0[r] = __builtin_amdgcn_exp2f(st0[r]);
        #pragma unroll
        for (int r = 0; r < 16; ++r) st1[r] = __builtin_amdgcn_exp2f(st1[r]);

        // ---- row-sum: per-lane pairwise tree; cross-half shuffle deferred
        {
            float s2[16];
            #pragma unroll
            for (int r = 0; r < 16; ++r) s2[r] = st0[r] + st1[r];
            float s4[8];
            #pragma unroll
            for (int r = 0; r < 8; ++r) s4[r] = s2[r] + s2[r + 8];
            float s8[4];
            #pragma unroll
            for (int r = 0; r < 4; ++r) s8[r] = s4[r] + s4[r + 4];
            l += (s8[0] + s8[1]) + (s8[2] + s8[3]);
        }

        // ---- pack P to bf16 (v_cvt_pk) + permlane32_swap -> PV A-frags; PV MFMAs
        __builtin_amdgcn_s_setprio(1);
        #pragma unroll
        for (int kvm = 0; kvm < 2; ++kvm) {
            #pragma unroll
            for (int tt = 0; tt < 2; ++tt) {
                float p0, p1, p2, p3, p4, p5, p6, p7;
                if (kvm == 0) {
                    p0 = st0[8*tt+0]; p1 = st0[8*tt+1]; p2 = st0[8*tt+2]; p3 = st0[8*tt+3];
                    p4 = st0[8*tt+4]; p5 = st0[8*tt+5]; p6 = st0[8*tt+6]; p7 = st0[8*tt+7];
                } else {
                    p0 = st1[8*tt+0]; p1 = st1[8*tt+1]; p2 = st1[8*tt+2]; p3 = st1[8*tt+3];
                    p4 = st1[8*tt+4]; p5 = st1[8*tt+5]; p6 = st1[8*tt+6]; p7 = st1[8*tt+7];
                }
                unsigned a0 = cvtpk(p0, p1);
                unsigned a1 = cvtpk(p2, p3);
                unsigned b0 = cvtpk(p4, p5);
                unsigned b1 = cvtpk(p6, p7);
                u32x2v r0 = __builtin_amdgcn_permlane32_swap(a0, b0, false, false);
                u32x2v r1 = __builtin_amdgcn_permlane32_swap(a1, b1, false, false);
                u32x4 fw = {r0[0], r1[0], r0[1], r1[1]};
                bf16x8 pf = *reinterpret_cast<bf16x8*>(&fw);
                const int km = kvm * 2 + tt;
                bf16x8 vf0 = *reinterpret_cast<const bf16x8*>(
                    Vsh + q31 * 128 + ((km * 32 + hi * 16) ^ kx));
                bf16x8 vf1 = *reinterpret_cast<const bf16x8*>(
                    Vsh + (q31 + 32) * 128 + ((km * 32 + hi * 16) ^ kx));
                acc0 = mfma32(pf, vf0, acc0);
                acc1 = mfma32(pf, vf1, acc1);
            }
        }
        __builtin_amdgcn_s_setprio(0);

        if (has_next) {
            __syncthreads();
            *reinterpret_cast<bf16x8*>(Ksh + soff0) = kr0;
            *reinterpret_cast<bf16x8*>(Ksh + soff1) = kr1;
            *reinterpret_cast<bf16x8*>(Vsh + soff0) = vr0;
            *reinterpret_cast<bf16x8*>(Vsh + soff1) = vr1;
            __syncthreads();
        }
    }

    // ---- deferred cross-half sum, combine halves, O = acc/l
    l += __shfl_xor(l, 32);
    lsh[wid][q31] = l;
    __syncthreads();
    float* fs = (float*)smem;
    if (half == 1) {
        float* dst = fs + wq * 2048;
        #pragma unroll
        for (int r = 0; r < 16; ++r) {
            dst[r * 64 + lane] = acc0[r];
            dst[(16 + r) * 64 + lane] = acc1[r];
        }
    }
    __syncthreads();
    if (half == 0) {
        const float* src = fs + wq * 2048;
        float ltot = l + lsh[wid + 4][q31];
        float inv = 1.0f / ltot;
        #pragma unroll
        for (int r = 0; r < 16; ++r) {
            const int qlr = (r & 3) + 8 * (r >> 2) + 4 * hi;
            float o0 = (acc0[r] + src[r * 64 + lane]) * inv;
            float o1 = (acc1[r] + src[(16 + r) * 64 + lane]) * inv;
            size_t o = (size_t)(b * Nn + qw0 + qlr) * Cc + h * Dd + q31;
            Ao[o]      = f2bf(o0);
            Ao[o + 32] = f2bf(o1);
        }
    }
}

extern "C" void kernel_launch(void* const* d_in, const int* in_sizes, int n_in,
                              void* d_out, int out_size, void* d_ws, size_t ws_size,
                              hipStream_t stream) {
    const float* hs = (const float*)d_in[0];
    const float* wq = (const float*)d_in[1];
    const float* wk = (const float*)d_in[2];
    const float* wv = (const float*)d_in[3];
    const float* wo = (const float*)d_in[4];
    const float* bo = (const float*)d_in[5];
    float* out = (float*)d_out;

    ushort* Xb   = (ushort*)d_ws;           // [8192][640]       5,242,880 u16
    ushort* Wqb  = Xb + 5242880;            // [640][640]          409,600
    ushort* Wkb  = Wqb + 409600;
    ushort* Wvb  = Wkb + 409600;
    ushort* Wob  = Wvb + 409600;
    ushort* Qh   = Wob + 409600;            // [4][10][2048][64] 5,242,880
    ushort* K16  = Qh + 5242880;            // [2][10][2048][64] 2,621,440
    ushort* Vt16 = K16 + 2621440;           // [2][10][64][2048] 2,621,440
    ushort* Aob  = Vt16 + 2621440;          // [4][2048][640]    5,242,880
    float*  Pstats = (float*)(Aob + 5242880); // [40][16][2][64]  81,920 f

    tobf16_all<<<3360, 256, 0, stream>>>(hs, wq, wk, wv, wo, Xb, Wqb, Wkb, Wvb, Wob);

    gemm_qkv<<<dim3(128, 10), 256, 0, stream>>>(Xb, Wqb, Wkb, Wvb, Qh, K16, Vt16, Pstats);
    attn_mfma<<<dim3(40, 16), 512, 0, stream>>>(Qh, Pstats, K16, Vt16, Aob);
    gemm_out<<<dim3(64, 10), 256, 0, stream>>>(Aob, Wob, out, bo, hs);
}

// Round 15
// 117.114 us; speedup vs baseline: 1.1172x; 1.1172x over previous
//
#include <hip/hip_runtime.h>
#include <hip/hip_bf16.h>
#include <math.h>

#define Bb 4
#define Nn 2048
#define Cc 640
#define Hh 10
#define Dd 64
#define EPSf 1e-5f
// ATTN_SCALE * log2(e), folded into Q affine so softmax is raw exp2
#define QSCALE 0.18033688f
#define KVT 64

typedef __attribute__((ext_vector_type(8))) short bf16x8;
typedef __attribute__((ext_vector_type(4))) float f32x4;
typedef __attribute__((ext_vector_type(16))) float f32x16;
typedef __attribute__((ext_vector_type(8))) unsigned short u16x8;
typedef __attribute__((ext_vector_type(4))) unsigned int u32x4;
typedef __attribute__((ext_vector_type(2))) unsigned int u32x2v;

__device__ inline unsigned short f2bf(float f) {
    unsigned int x = __float_as_uint(f);
    unsigned int r = (x + 0x7fffu + ((x >> 16) & 1u)) >> 16;
    return (unsigned short)r;
}
__device__ inline float bf2f(unsigned short v) {
    return __uint_as_float(((unsigned int)v) << 16);
}
__device__ inline unsigned pkbf(float a, float b) {
    __hip_bfloat162 t = __float22bfloat162_rn(float2{a, b});
    union { __hip_bfloat162 h; unsigned u; } cv; cv.h = t;
    return cv.u;
}
// single-instruction packed f32->bf16 (hot path only; <=1ulp vs RN)
__device__ inline unsigned cvtpk(float lo, float hi) {
    unsigned r;
    asm("v_cvt_pk_bf16_f32 %0, %1, %2" : "=v"(r) : "v"(lo), "v"(hi));
    return r;
}
__device__ inline f32x4 mfma16(bf16x8 a, bf16x8 b, f32x4 c) {
    return __builtin_amdgcn_mfma_f32_16x16x32_bf16(a, b, c, 0, 0, 0);
}
__device__ inline f32x16 mfma32(bf16x8 a, bf16x8 b, f32x16 c) {
    return __builtin_amdgcn_mfma_f32_32x32x16_bf16(a, b, c, 0, 0, 0);
}
// async global->LDS, 16B per lane; lds base must be wave-uniform (HW adds lane*16)
__device__ inline void gl16(const ushort* g, char* l) {
    __builtin_amdgcn_global_load_lds(
        (const __attribute__((address_space(1))) unsigned int*)g,
        (__attribute__((address_space(3))) unsigned int*)l, 16, 0, 0);
}

// ---------------- fused fp32 -> bf16 conversion for hs + 4 weights ----------------
__global__ __launch_bounds__(256)
void tobf16_all(const float* __restrict__ hs, const float* __restrict__ wq,
                const float* __restrict__ wk, const float* __restrict__ wv,
                const float* __restrict__ wo,
                ushort* __restrict__ Xb, ushort* __restrict__ Wqb,
                ushort* __restrict__ Wkb, ushort* __restrict__ Wvb,
                ushort* __restrict__ Wob) {
    const int bid = blockIdx.x;
    const float* src;
    ushort* dst;
    int i;
    if (bid < 2560) {
        src = hs; dst = Xb; i = bid * 256 + threadIdx.x;
    } else {
        int w = (bid - 2560) / 200;
        int rb = (bid - 2560) % 200;
        src = (w == 0) ? wq : (w == 1) ? wk : (w == 2) ? wv : wo;
        dst = (w == 0) ? Wqb : (w == 1) ? Wkb : (w == 2) ? Wvb : Wob;
        i = rb * 256 + threadIdx.x;
    }
    const size_t base = (size_t)i * 8;
    float4 a = *reinterpret_cast<const float4*>(src + base);
    float4 b = *reinterpret_cast<const float4*>(src + base + 4);
    u16x8 o;
    o[0] = f2bf(a.x); o[1] = f2bf(a.y); o[2] = f2bf(a.z); o[3] = f2bf(a.w);
    o[4] = f2bf(b.x); o[5] = f2bf(b.y); o[6] = f2bf(b.z); o[7] = f2bf(b.w);
    *reinterpret_cast<u16x8*>(dst + base) = o;
}

// ---------------- bf16 MFMA GEMM-BT body: OUT[r,o] = sum_c X[r,c] * W[o,c] ----------------
// MODE 0 additionally accumulates per-(bh,slot,d) column sums/sumsq into Pstats.
template<int MODE>
__device__ __forceinline__ void gemm_body(
    const ushort* __restrict__ X, const ushort* __restrict__ W,
    ushort* __restrict__ outh, float* __restrict__ outf,
    const float* __restrict__ bo, const float* __restrict__ hs,
    float* __restrict__ Pstats,
    int mt, int h, char* As, char* Bs)
{
    const int tid = threadIdx.x;
    const int wv = tid >> 6, lane = tid & 63;
    const int c = lane & 15, g = lane >> 4;
    const int r0 = mt * 128;
    const int xr0 = (MODE == 1 || MODE == 2) ? (r0 < Nn ? r0 : r0 + Nn) : r0;
    const int o0 = h * 64;

    const int grow = lane >> 3;
    const int gcol = ((((lane & 7) * 16) ^ ((lane >> 3) << 4)) >> 1);

    f32x4 acc[2][4];
    #pragma unroll
    for (int i = 0; i < 2; ++i)
        #pragma unroll
        for (int j = 0; j < 4; ++j)
            acc[i][j] = (f32x4){0.f, 0.f, 0.f, 0.f};

    for (int k0 = 0; k0 < Cc; k0 += 64) {
        __syncthreads();
        #pragma unroll
        for (int i = 0; i < 4; ++i) {
            int a = wv * 4 + i;
            gl16(X + (size_t)(xr0 + a * 8 + grow) * Cc + k0 + gcol, As + a * 1024);
        }
        #pragma unroll
        for (int i = 0; i < 2; ++i) {
            int bb = wv * 2 + i;
            gl16(W + (size_t)(o0 + bb * 8 + grow) * Cc + k0 + gcol, Bs + bb * 1024);
        }
        __syncthreads();

        bf16x8 xf[2][2], wf[4][2];
        #pragma unroll
        for (int rt = 0; rt < 2; ++rt) {
            int row = wv * 32 + rt * 16 + c;
            #pragma unroll
            for (int ks = 0; ks < 2; ++ks)
                xf[rt][ks] = *reinterpret_cast<const bf16x8*>(
                    As + row * 128 + ((ks * 64 + g * 16) ^ ((row & 7) << 4)));
        }
        #pragma unroll
        for (int ct = 0; ct < 4; ++ct) {
            int row = ct * 16 + c;
            #pragma unroll
            for (int ks = 0; ks < 2; ++ks)
                wf[ct][ks] = *reinterpret_cast<const bf16x8*>(
                    Bs + row * 128 + ((ks * 64 + g * 16) ^ ((row & 7) << 4)));
        }
        #pragma unroll
        for (int rt = 0; rt < 2; ++rt)
            #pragma unroll
            for (int ct = 0; ct < 4; ++ct)
                #pragma unroll
                for (int ks = 0; ks < 2; ++ks) {
                    if constexpr (MODE == 2)
                        acc[rt][ct] = mfma16(xf[rt][ks], wf[ct][ks], acc[rt][ct]);
                    else
                        acc[rt][ct] = mfma16(wf[ct][ks], xf[rt][ks], acc[rt][ct]);
                }
    }

    if constexpr (MODE == 0 || MODE == 1) {
        #pragma unroll
        for (int rt = 0; rt < 2; ++rt) {
            int r = r0 + wv * 32 + rt * 16 + c;
            int bi = r >> 11, n = r & 2047;
            #pragma unroll
            for (int ct = 0; ct < 4; ++ct) {
                int d0 = ct * 16 + g * 4;
                ushort4 v4;
                v4.x = f2bf(acc[rt][ct][0]); v4.y = f2bf(acc[rt][ct][1]);
                v4.z = f2bf(acc[rt][ct][2]); v4.w = f2bf(acc[rt][ct][3]);
                *reinterpret_cast<ushort4*>(&outh[(((size_t)(bi * Hh + h)) * Nn + n) * Dd + d0]) = v4;
            }
        }
    } else if constexpr (MODE == 2) {
        #pragma unroll
        for (int rt = 0; rt < 2; ++rt) {
            int r = r0 + wv * 32 + rt * 16 + g * 4;
            int kb = r >> 11, n = r & 2047;
            #pragma unroll
            for (int ct = 0; ct < 4; ++ct) {
                int d = ct * 16 + c;
                ushort4 v4;
                v4.x = f2bf(acc[rt][ct][0]); v4.y = f2bf(acc[rt][ct][1]);
                v4.z = f2bf(acc[rt][ct][2]); v4.w = f2bf(acc[rt][ct][3]);
                *reinterpret_cast<ushort4*>(&outh[(((size_t)(kb * Hh + h)) * Dd + d) * Nn + n]) = v4;
            }
        }
    } else {
        #pragma unroll
        for (int rt = 0; rt < 2; ++rt) {
            int r = r0 + wv * 32 + rt * 16 + c;
            #pragma unroll
            for (int ct = 0; ct < 4; ++ct) {
                int o = h * 64 + ct * 16 + g * 4;
                float4 bvv = *reinterpret_cast<const float4*>(&bo[o]);
                float4 hv = *reinterpret_cast<const float4*>(&hs[(size_t)r * Cc + o]);
                float4 ov;
                ov.x = acc[rt][ct][0] + bvv.x + hv.x;
                ov.y = acc[rt][ct][1] + bvv.y + hv.y;
                ov.z = acc[rt][ct][2] + bvv.z + hv.z;
                ov.w = acc[rt][ct][3] + bvv.w + hv.w;
                *reinterpret_cast<float4*>(&outf[(size_t)r * Cc + o]) = ov;
            }
        }
    }

    if constexpr (MODE == 0) {
        // ---- fused Q-stats: column sums/sumsq over this block's 128 rows
        __syncthreads();                       // all waves done reading As/Bs
        float* Sw  = (float*)As;               // [4][64]
        float* Sw2 = (float*)(As + 1024);      // [4][64]
        #pragma unroll
        for (int ct = 0; ct < 4; ++ct) {
            #pragma unroll
            for (int rg = 0; rg < 4; ++rg) {
                float a0 = acc[0][ct][rg], a1 = acc[1][ct][rg];
                float v = a0 + a1;
                float q = a0 * a0 + a1 * a1;
                #pragma unroll
                for (int m = 1; m < 16; m <<= 1) {
                    v += __shfl_xor(v, m);
                    q += __shfl_xor(q, m);
                }
                if (c == 0) {
                    int d = ct * 16 + g * 4 + rg;
                    Sw[wv * 64 + d] = v;
                    Sw2[wv * 64 + d] = q;
                }
            }
        }
        __syncthreads();
        if (tid < 64) {
            float s = Sw[tid] + Sw[64 + tid] + Sw[128 + tid] + Sw[192 + tid];
            float q = Sw2[tid] + Sw2[64 + tid] + Sw2[128 + tid] + Sw2[192 + tid];
            int bi = mt >> 4, slot = mt & 15;
            int bh = bi * Hh + h;
            float* p = Pstats + ((size_t)(bh * 16 + slot) * 2) * 64;
            p[tid] = s;
            p[64 + tid] = q;
        }
    }
}

// Q, K, V projections fused into one 1280-block launch
__global__ __launch_bounds__(256)
void gemm_qkv(const ushort* __restrict__ X, const ushort* __restrict__ Wq,
              const ushort* __restrict__ Wk, const ushort* __restrict__ Wv,
              ushort* __restrict__ Qh, ushort* __restrict__ K16,
              ushort* __restrict__ Vt16, float* __restrict__ Pstats) {
    __shared__ alignas(16) char As[16384];
    __shared__ alignas(16) char Bs[8192];
    const int bx = blockIdx.x;
    if (bx < 64)
        gemm_body<0>(X, Wq, Qh, nullptr, nullptr, nullptr, Pstats, bx, blockIdx.y, As, Bs);
    else if (bx < 96)
        gemm_body<1>(X, Wk, K16, nullptr, nullptr, nullptr, nullptr, bx - 64, blockIdx.y, As, Bs);
    else
        gemm_body<2>(X, Wv, Vt16, nullptr, nullptr, nullptr, nullptr, bx - 96, blockIdx.y, As, Bs);
}

__global__ __launch_bounds__(256)
void gemm_out(const ushort* __restrict__ Ain, const ushort* __restrict__ Wo,
              float* __restrict__ out, const float* __restrict__ bo,
              const float* __restrict__ hs) {
    __shared__ alignas(16) char As[16384];
    __shared__ alignas(16) char Bs[8192];
    gemm_body<3>(Ain, Wo, nullptr, out, bo, hs, nullptr, blockIdx.x, blockIdx.y, As, Bs);
}

// ---------------- bf16 MFMA flash attention, v12 ----------------
// R12-proven single-buffer structure + LDS-stats prologue (NO setprio).
// grid (40 bh, 16 qtiles), 8 waves (512 thr), waves 0-3 kv [0,1024), waves 4-7
// kv [1024,2048), KV tile 64. Fused adain on Q load (stats reduced from Pstats).
// Shift-free softmax (bare v_exp_f32); P pack via v_cvt_pk_bf16_f32.
__global__ __launch_bounds__(512, 4)
void attn_mfma(const ushort* __restrict__ Qh, const float* __restrict__ Pstats,
               const ushort* __restrict__ Kb, const ushort* __restrict__ Vtb,
               ushort* __restrict__ Ao) {
    __shared__ alignas(16) char smem[32768];   // Ks[2][8192] | Vs[2][8192]
    __shared__ float lsh[8][32];
    __shared__ float statl[4][64];             // mS, sS, mT, sT

    const int tid = threadIdx.x;
    const int wid = tid >> 6, lane = tid & 63;
    const int half = wid >> 2, wq = wid & 3;
    const int q31 = lane & 31, hi = lane >> 5;
    const int bh = blockIdx.x, b = bh / Hh, h = bh % Hh, kb = b >> 1;
    const int qw0 = blockIdx.y * 128 + wq * 32;
    const int kv0 = half * (Nn / 2);

    char* Ksh = smem + half * 8192;
    char* Vsh = smem + 16384 + half * 8192;

    const ushort* qp = Qh + ((size_t)bh * Nn + qw0) * Dd;
    const ushort* kp = Kb + ((size_t)(kb * Hh + h) * Nn + kv0) * Dd;
    const ushort* vp = Vtb + ((size_t)(kb * Hh + h)) * Dd * Nn + kv0;

    // ---- reduce Q stats from per-tile partials (odd batches only)
    if (b & 1) {
        if (tid < 128) {
            const int which = tid >> 6;     // 0: self(bh), 1: style(bh-Hh)
            const int d = tid & 63;
            const int tb = which ? (bh - Hh) : bh;
            const float* p = Pstats + ((size_t)(tb * 16) * 2) * 64;
            float s = 0.f, q = 0.f;
            #pragma unroll
            for (int j = 0; j < 16; ++j) {
                s += p[(j * 2) * 64 + d];
                q += p[(j * 2 + 1) * 64 + d];
            }
            float mu = s / (float)Nn;
            float var = (q - (float)Nn * mu * mu) / (float)(Nn - 1);
            float sd = sqrtf(var + EPSf);
            statl[which * 2 + 0][d] = mu;
            statl[which * 2 + 1][d] = sd;
        }
        __syncthreads();
    }

    // ---- Q fragments with fused adain + QSCALE (once per wave)
    bf16x8 qf[4];
    #pragma unroll
    for (int dsl = 0; dsl < 4; ++dsl) {
        const int d0 = dsl * 16 + hi * 8;
        u16x8 qin = *reinterpret_cast<const u16x8*>(qp + (size_t)q31 * Dd + d0);
        float x[8];
        #pragma unroll
        for (int j = 0; j < 8; ++j) x[j] = bf2f(qin[j]);
        if (b & 1) {
            #pragma unroll
            for (int j = 0; j < 8; ++j) {
                float r = statl[3][d0 + j] / statl[1][d0 + j];
                x[j] = (x[j] * r + (statl[2][d0 + j] - statl[0][d0 + j] * r)) * QSCALE;
            }
        } else {
            #pragma unroll
            for (int j = 0; j < 8; ++j) x[j] *= QSCALE;
        }
        u32x4 pw = {pkbf(x[0], x[1]), pkbf(x[2], x[3]), pkbf(x[4], x[5]), pkbf(x[6], x[7])};
        qf[dsl] = *reinterpret_cast<bf16x8*>(&pw);
    }

    f32x16 acc0, acc1;
    #pragma unroll
    for (int r = 0; r < 16; ++r) { acc0[r] = 0.f; acc1[r] = 0.f; }
    float l = 0.f;

    const int htid = tid & 255;
    const int srow = htid >> 3, sch = htid & 7;
    const int swz = (sch * 16) ^ ((srow & 7) << 4);
    const int soff0 = srow * 128 + swz;
    const int soff1 = (srow + 32) * 128 + swz;
    const ushort* kg0 = kp + (size_t)srow * Dd + sch * 8;
    const ushort* kg1 = kp + (size_t)(srow + 32) * Dd + sch * 8;
    const ushort* vg0 = vp + (size_t)srow * Nn + sch * 8;
    const ushort* vg1 = vp + (size_t)(srow + 32) * Nn + sch * 8;

    bf16x8 kr0 = *reinterpret_cast<const bf16x8*>(kg0);
    bf16x8 kr1 = *reinterpret_cast<const bf16x8*>(kg1);
    bf16x8 vr0 = *reinterpret_cast<const bf16x8*>(vg0);
    bf16x8 vr1 = *reinterpret_cast<const bf16x8*>(vg1);
    *reinterpret_cast<bf16x8*>(Ksh + soff0) = kr0;
    *reinterpret_cast<bf16x8*>(Ksh + soff1) = kr1;
    *reinterpret_cast<bf16x8*>(Vsh + soff0) = vr0;
    *reinterpret_cast<bf16x8*>(Vsh + soff1) = vr1;
    __syncthreads();

    const int kx = (q31 & 7) << 4;

    for (int kt = 0; kt < Nn / 2; kt += KVT) {
        const bool has_next = (kt + KVT) < (Nn / 2);
        if (has_next) {
            kr0 = *reinterpret_cast<const bf16x8*>(kg0 + (size_t)(kt + KVT) * Dd);
            kr1 = *reinterpret_cast<const bf16x8*>(kg1 + (size_t)(kt + KVT) * Dd);
            vr0 = *reinterpret_cast<const bf16x8*>(vg0 + kt + KVT);
            vr1 = *reinterpret_cast<const bf16x8*>(vg1 + kt + KVT);
        }

        // ---- QK^T (swapped): A=K rows, B=Q rows
        f32x16 st0, st1;
        #pragma unroll
        for (int r = 0; r < 16; ++r) { st0[r] = 0.f; st1[r] = 0.f; }
        #pragma unroll
        for (int dsl = 0; dsl < 4; ++dsl) {
            bf16x8 kf0 = *reinterpret_cast<const bf16x8*>(
                Ksh + q31 * 128 + ((dsl * 32 + hi * 16) ^ kx));
            bf16x8 kf1 = *reinterpret_cast<const bf16x8*>(
                Ksh + (q31 + 32) * 128 + ((dsl * 32 + hi * 16) ^ kx));
            st0 = mfma32(kf0, qf[dsl], st0);
            st1 = mfma32(kf1, qf[dsl], st1);
        }

        // ---- P = exp2(s) raw, bare v_exp_f32 (shift-free softmax)
        #pragma unroll
        for (int r = 0; r < 16; ++r) st0[r] = __builtin_amdgcn_exp2f(st0[r]);
        #pragma unroll
        for (int r = 0; r < 16; ++r) st1[r] = __builtin_amdgcn_exp2f(st1[r]);

        // ---- row-sum: per-lane pairwise tree; cross-half shuffle deferred
        {
            float s2[16];
            #pragma unroll
            for (int r = 0; r < 16; ++r) s2[r] = st0[r] + st1[r];
            float s4[8];
            #pragma unroll
            for (int r = 0; r < 8; ++r) s4[r] = s2[r] + s2[r + 8];
            float s8[4];
            #pragma unroll
            for (int r = 0; r < 4; ++r) s8[r] = s4[r] + s4[r + 4];
            l += (s8[0] + s8[1]) + (s8[2] + s8[3]);
        }

        // ---- pack P to bf16 (v_cvt_pk) + permlane32_swap -> PV A-frags; PV MFMAs
        #pragma unroll
        for (int kvm = 0; kvm < 2; ++kvm) {
            #pragma unroll
            for (int tt = 0; tt < 2; ++tt) {
                float p0, p1, p2, p3, p4, p5, p6, p7;
                if (kvm == 0) {
                    p0 = st0[8*tt+0]; p1 = st0[8*tt+1]; p2 = st0[8*tt+2]; p3 = st0[8*tt+3];
                    p4 = st0[8*tt+4]; p5 = st0[8*tt+5]; p6 = st0[8*tt+6]; p7 = st0[8*tt+7];
                } else {
                    p0 = st1[8*tt+0]; p1 = st1[8*tt+1]; p2 = st1[8*tt+2]; p3 = st1[8*tt+3];
                    p4 = st1[8*tt+4]; p5 = st1[8*tt+5]; p6 = st1[8*tt+6]; p7 = st1[8*tt+7];
                }
                unsigned a0 = cvtpk(p0, p1);
                unsigned a1 = cvtpk(p2, p3);
                unsigned b0 = cvtpk(p4, p5);
                unsigned b1 = cvtpk(p6, p7);
                u32x2v r0 = __builtin_amdgcn_permlane32_swap(a0, b0, false, false);
                u32x2v r1 = __builtin_amdgcn_permlane32_swap(a1, b1, false, false);
                u32x4 fw = {r0[0], r1[0], r0[1], r1[1]};
                bf16x8 pf = *reinterpret_cast<bf16x8*>(&fw);
                const int km = kvm * 2 + tt;
                bf16x8 vf0 = *reinterpret_cast<const bf16x8*>(
                    Vsh + q31 * 128 + ((km * 32 + hi * 16) ^ kx));
                bf16x8 vf1 = *reinterpret_cast<const bf16x8*>(
                    Vsh + (q31 + 32) * 128 + ((km * 32 + hi * 16) ^ kx));
                acc0 = mfma32(pf, vf0, acc0);
                acc1 = mfma32(pf, vf1, acc1);
            }
        }

        if (has_next) {
            __syncthreads();
            *reinterpret_cast<bf16x8*>(Ksh + soff0) = kr0;
            *reinterpret_cast<bf16x8*>(Ksh + soff1) = kr1;
            *reinterpret_cast<bf16x8*>(Vsh + soff0) = vr0;
            *reinterpret_cast<bf16x8*>(Vsh + soff1) = vr1;
            __syncthreads();
        }
    }

    // ---- deferred cross-half sum, combine halves, O = acc/l
    l += __shfl_xor(l, 32);
    lsh[wid][q31] = l;
    __syncthreads();
    float* fs = (float*)smem;
    if (half == 1) {
        float* dst = fs + wq * 2048;
        #pragma unroll
        for (int r = 0; r < 16; ++r) {
            dst[r * 64 + lane] = acc0[r];
            dst[(16 + r) * 64 + lane] = acc1[r];
        }
    }
    __syncthreads();
    if (half == 0) {
        const float* src = fs + wq * 2048;
        float ltot = l + lsh[wid + 4][q31];
        float inv = 1.0f / ltot;
        #pragma unroll
        for (int r = 0; r < 16; ++r) {
            const int qlr = (r & 3) + 8 * (r >> 2) + 4 * hi;
            float o0 = (acc0[r] + src[r * 64 + lane]) * inv;
            float o1 = (acc1[r] + src[(16 + r) * 64 + lane]) * inv;
            size_t o = (size_t)(b * Nn + qw0 + qlr) * Cc + h * Dd + q31;
            Ao[o]      = f2bf(o0);
            Ao[o + 32] = f2bf(o1);
        }
    }
}

extern "C" void kernel_launch(void* const* d_in, const int* in_sizes, int n_in,
                              void* d_out, int out_size, void* d_ws, size_t ws_size,
                              hipStream_t stream) {
    const float* hs = (const float*)d_in[0];
    const float* wq = (const float*)d_in[1];
    const float* wk = (const float*)d_in[2];
    const float* wv = (const float*)d_in[3];
    const float* wo = (const float*)d_in[4];
    const float* bo = (const float*)d_in[5];
    float* out = (float*)d_out;

    ushort* Xb   = (ushort*)d_ws;           // [8192][640]       5,242,880 u16
    ushort* Wqb  = Xb + 5242880;            // [640][640]          409,600
    ushort* Wkb  = Wqb + 409600;
    ushort* Wvb  = Wkb + 409600;
    ushort* Wob  = Wvb + 409600;
    ushort* Qh   = Wob + 409600;            // [4][10][2048][64] 5,242,880
    ushort* K16  = Qh + 5242880;            // [2][10][2048][64] 2,621,440
    ushort* Vt16 = K16 + 2621440;           // [2][10][64][2048] 2,621,440
    ushort* Aob  = Vt16 + 2621440;          // [4][2048][640]    5,242,880
    float*  Pstats = (float*)(Aob + 5242880); // [40][16][2][64]  81,920 f

    tobf16_all<<<3360, 256, 0, stream>>>(hs, wq, wk, wv, wo, Xb, Wqb, Wkb, Wvb, Wob);

    gemm_qkv<<<dim3(128, 10), 256, 0, stream>>>(Xb, Wqb, Wkb, Wvb, Qh, K16, Vt16, Pstats);
    attn_mfma<<<dim3(40, 16), 512, 0, stream>>>(Qh, Pstats, K16, Vt16, Aob);
    gemm_out<<<dim3(64, 10), 256, 0, stream>>>(Aob, Wob, out, bo, hs);
}